// Round 1
// 513.942 us; speedup vs baseline: 1.0263x; 1.0263x over previous
//
#include <hip/hip_runtime.h>
#include <cstdint>
#include <cstddef>

#define BATCH 2048
#define VOCAB 50257
#define TOPK  512
#define CAND_MAX 4096
#define BLOCK 256
#define NWAVE (BLOCK / 64)
#define WSEG  (CAND_MAX / NWAVE)   // 1024 slots per wave-private segment

// Native clang vector type — __builtin_nontemporal_load requires this.
typedef float vfloat4 __attribute__((ext_vector_type(4)));

// Monotone mapping: float -> unsigned such that key order == value order.
__device__ __forceinline__ unsigned fkey(float f) {
    unsigned u = __float_as_uint(f);
    return (u & 0x80000000u) ? ~u : (u | 0x80000000u);
}
__device__ __forceinline__ float unfkey(unsigned k) {
    unsigned u = (k & 0x80000000u) ? (k & 0x7FFFFFFFu) : ~k;
    return __uint_as_float(u);
}

__global__ __launch_bounds__(BLOCK) void topk_ce_kernel(
    const float* __restrict__ feats,
    const int*   __restrict__ labels,
    float*       __restrict__ out)
{
    __shared__ float    cand[CAND_MAX];
    __shared__ int      s_wc[NWAVE];
    __shared__ unsigned s_hist[256];
    __shared__ unsigned s_sfx[256];
    __shared__ unsigned s_wtot[NWAVE];
    __shared__ int      s_dig, s_above;
    __shared__ float    s_psum[NWAVE];
    __shared__ float    s_pcnt[NWAVE];

    const int row  = blockIdx.x;
    const int tid  = threadIdx.x;
    const int lane = tid & 63;
    const int wid  = tid >> 6;
    const float* rp = feats + (size_t)row * VOCAB;

    // Row base is only 4B-aligned (VOCAB*4 % 16 == 4). Peel to 16B alignment.
    uintptr_t a = (uintptr_t)rp;
    int head = ((int)((16u - (a & 15u)) & 15u)) >> 2;
    if (head > VOCAB) head = VOCAB;
    const int nvec = (VOCAB - head) >> 2;
    const int tailstart = head + nvec * 4;
    const vfloat4* vp = (const vfloat4*)(rp + head);
    const int nfull = nvec / (BLOCK * 4);
    const int restart = nfull * BLOCK * 4;

    const float NEGINF = -__builtin_inff();

    float thresh = 2.0f;
    float blo = 0.0f, bhi = 0.0f;
    bool  has_lo = false, has_hi = false;
    float step = 1.0f;

    // Branchless-append: ballot + mbcnt prefix + predicated fire-and-forget
    // ds_write into a wave-private segment. Write cursor (wbase) is
    // wave-uniform -> stays in SGPR (s_bcnt1 of the ballot). No LDS atomic,
    // no lgkmcnt round-trip in the scan's dependency chain.
#define APPEND1(x) do { \
        bool p_ = (x) > thresh; \
        unsigned long long m_ = __ballot(p_); \
        if (m_) { \
            int pre_ = __builtin_amdgcn_mbcnt_hi((unsigned)(m_ >> 32), \
                         __builtin_amdgcn_mbcnt_lo((unsigned)m_, 0u)); \
            int pos_ = wbase + pre_; \
            if (p_ && pos_ < wlimit) cand[pos_] = (x); \
            wbase += (int)__popcll(m_); \
        } } while (0)
#define APPEND4(v) do { APPEND1((v).x); APPEND1((v).y); APPEND1((v).z); APPEND1((v).w); } while (0)

    for (int attempt = 0; attempt < 40; ++attempt) {
        int wbase = wid * WSEG;           // wave-uniform write cursor
        const int wstart = wbase;
        const int wlimit = wstart + WSEG;

        // Head peel: uniform trip count, guarded load (keeps wbase uniform).
        for (int i0 = 0; i0 < head; i0 += BLOCK) {
            int i = i0 + tid;
            float v = NEGINF;
            if (i < head) v = rp[i];
            APPEND1(v);
        }

        // Main body with manual 1-iteration prefetch: next 4 KB/wave issued
        // before processing the current 4 KB -> loads always in flight.
        if (nfull > 0) {
            vfloat4 n0 = __builtin_nontemporal_load(&vp[tid]);
            vfloat4 n1 = __builtin_nontemporal_load(&vp[tid + BLOCK]);
            vfloat4 n2 = __builtin_nontemporal_load(&vp[tid + 2 * BLOCK]);
            vfloat4 n3 = __builtin_nontemporal_load(&vp[tid + 3 * BLOCK]);
            for (int it = 0; it < nfull; ++it) {
                vfloat4 c0 = n0, c1 = n1, c2 = n2, c3 = n3;
                if (it + 1 < nfull) {  // uniform branch
                    const int bn = (it + 1) * (BLOCK * 4) + tid;
                    n0 = __builtin_nontemporal_load(&vp[bn]);
                    n1 = __builtin_nontemporal_load(&vp[bn + BLOCK]);
                    n2 = __builtin_nontemporal_load(&vp[bn + 2 * BLOCK]);
                    n3 = __builtin_nontemporal_load(&vp[bn + 3 * BLOCK]);
                }
                APPEND4(c0); APPEND4(c1); APPEND4(c2); APPEND4(c3);
            }
        }

        // Vector remainder: uniform trip count, guarded loads.
        for (int i0 = restart; i0 < nvec; i0 += BLOCK) {
            int i = i0 + tid;
            vfloat4 v = { NEGINF, NEGINF, NEGINF, NEGINF };
            if (i < nvec) v = __builtin_nontemporal_load(&vp[i]);
            APPEND4(v);
        }
        // Scalar tail: uniform trip count, guarded loads.
        for (int i0 = tailstart; i0 < VOCAB; i0 += BLOCK) {
            int i = i0 + tid;
            float v = NEGINF;
            if (i < VOCAB) v = rp[i];
            APPEND1(v);
        }

        if (lane == 0) s_wc[wid] = wbase - wstart;  // uncapped count
        __syncthreads();
        int total = 0, wmax = 0;
#pragma unroll
        for (int w = 0; w < NWAVE; ++w) {
            int c = s_wc[w];
            total += c;
            if (c > wmax) wmax = c;
        }
        // Band check mirrors the original; per-wave overflow (adversarial
        // clustering) folds into the "too many" branch since it implies
        // total > WSEG >= TOPK.
        if (total >= TOPK && total <= CAND_MAX && wmax <= WSEG) break;
        if (total < TOPK) { bhi = thresh; has_hi = true; }
        else              { blo = thresh; has_lo = true; }
        if (has_lo && has_hi)      thresh = 0.5f * (blo + bhi);
        else if (has_lo)          { thresh = blo + step; step *= 2.0f; }
        else                      { thresh = bhi - step; step *= 2.0f; }
        __syncthreads();
    }
#undef APPEND1
#undef APPEND4

    int wc_mine = s_wc[wid]; if (wc_mine > WSEG) wc_mine = WSEG;
    int m_stored = 0;
#pragma unroll
    for (int w = 0; w < NWAVE; ++w) {
        int c = s_wc[w];
        m_stored += (c > WSEG) ? WSEG : c;
    }
    if (m_stored == 0) return;  // pathological; contributes nothing
    const int kk = (TOPK < m_stored) ? TOPK : m_stored;
    const int segbase = wid * WSEG;

    // --- Exact radix select (MSB-first, 8-bit digits) for the kk-th largest
    // key. Each wave histograms its own segment (wave-aggregated leader
    // atomic on the near-degenerate rounds). Suffix sums via in-wave shfl
    // scan + cross-wave fixup: ~6 barriers/round instead of 19.
    unsigned pref = 0, maskhi = 0;
    int remain = kk;

    for (int sh = 24; sh >= 0; sh -= 8) {
        s_hist[tid] = 0;  // BLOCK == 256
        __syncthreads();

        for (int i = lane; i < wc_mine; i += 64) {
            unsigned key = fkey(cand[segbase + i]);
            bool match = ((key & maskhi) == pref);
            unsigned dig = (key >> sh) & 255u;
            unsigned long long mm = __ballot(match);
            if (mm) {
                int leader = __ffsll((unsigned long long)mm) - 1;
                unsigned ldig = __shfl(dig, leader);
                unsigned long long same = __ballot(match && (dig == ldig));
                if (same == mm) {
                    if (lane == leader)
                        atomicAdd(&s_hist[ldig], (unsigned)__popcll(mm));
                } else if (match) {
                    atomicAdd(&s_hist[dig], 1u);
                }
            }
        }
        __syncthreads();

        // In-wave suffix scan over this wave's 64 bins (no barriers).
        unsigned v = s_hist[tid];
#pragma unroll
        for (int off = 1; off < 64; off <<= 1) {
            unsigned o = __shfl_down(v, off);
            if (lane + off < 64) v += o;
        }
        if (lane == 0) s_wtot[wid] = v;  // wave's 64-bin total
        __syncthreads();
        unsigned addv = 0;
#pragma unroll
        for (int w = 0; w < NWAVE; ++w)
            if (w > wid) addv += s_wtot[w];
        unsigned my = v + addv;          // full suffix sum at bin=tid
        s_sfx[tid] = my;
        __syncthreads();
        unsigned nxt = (tid < 255) ? s_sfx[tid + 1] : 0u;
        if ((int)my >= remain && (tid == 255 || (int)nxt < remain)) {
            s_dig = tid;
            s_above = (int)nxt;
        }
        __syncthreads();
        remain -= s_above;
        pref   |= ((unsigned)s_dig) << sh;
        maskhi |= (0xFFu << sh);
        __syncthreads();
    }

    // pref is now the exact key of the kk-th largest value t.
    const float tval = unfkey(pref);

    // Sum exp over strictly-greater values; add (kk - c_gt) copies of exp(t)
    // to handle ties exactly like top_k does. Each wave sums its own segment.
    float psum = 0.0f, pcnt = 0.0f;
    for (int i = lane; i < wc_mine; i += 64) {
        float v = cand[segbase + i];
        if (fkey(v) > pref) { psum += expf(v); pcnt += 1.0f; }
    }
#pragma unroll
    for (int off = 32; off > 0; off >>= 1) {
        psum += __shfl_down(psum, off);
        pcnt += __shfl_down(pcnt, off);
    }
    if (lane == 0) { s_psum[wid] = psum; s_pcnt[wid] = pcnt; }
    __syncthreads();
    if (tid == 0) {
        float sum = 0.0f, cnt = 0.0f;
        for (int w = 0; w < NWAVE; ++w) { sum += s_psum[w]; cnt += s_pcnt[w]; }
        sum += ((float)kk - cnt) * expf(tval);
        float fl = rp[labels[row]];
        float loss = logf(sum) - fl;
        atomicAdd(out, loss * (1.0f / (float)BATCH));
    }
}

extern "C" void kernel_launch(void* const* d_in, const int* in_sizes, int n_in,
                              void* d_out, int out_size, void* d_ws, size_t ws_size,
                              hipStream_t stream) {
    const float* feats  = (const float*)d_in[0];
    const int*   labels = (const int*)d_in[1];
    // d_in[2] holds k = 512; fixed at compile time as TOPK.
    float* out = (float*)d_out;
    (void)in_sizes; (void)n_in; (void)out_size; (void)d_ws; (void)ws_size;

    // d_out is re-poisoned (0xAA) before every replay; zero it on-stream.
    (void)hipMemsetAsync(out, 0, sizeof(float), stream);
    topk_ce_kernel<<<BATCH, BLOCK, 0, stream>>>(feats, labels, out);
}